// Round 6
// baseline (88.997 us; speedup 1.0000x reference)
//
#include <hip/hip_runtime.h>

// QConv2d v6: v5 + NON-DRAINING inter-strip barriers.
// __syncthreads() emits s_waitcnt vmcnt(0) before s_barrier (m97), which forced
// each strip's 64KB/CU of global stores to drain before producers could publish
// the next strip -> re-serialized stores. Correctness across the barrier needs
// only LDS visibility: producer ds_writes drained (lgkmcnt(0)) + s_barrier.
// Global stores have no consumer -> legally stay in flight. Raw inline-asm
// barrier keeps them pipelined; only the final strip's drain is exposed.
//
// Grid 256 (1 block/CU = batch), TPB 512 (8 waves).
// Waves 0-3 (producers): load rho block (c1,c2), contract qy,py (uy), wave-private
//   LDS transpose, contract qx (ux) -> Y[px][qx'] in regs. 4 strips: compute 2 px'
//   rows of W into LDS (disjoint rows per strip), barrier, all 8 waves store 64 KB.

#define TPB 512

#define BARRIER_LDS_ONLY() asm volatile("s_waitcnt lgkmcnt(0)\n\ts_barrier" ::: "memory")

__global__ __launch_bounds__(TPB, 2) void qconv_fused(
    const float* __restrict__ rho,   // [256][128][128]
    const float* __restrict__ ux,    // [8][8]
    const float* __restrict__ uy,    // [8][8]
    const float* __restrict__ uc,    // [4][4]
    float* __restrict__ out)         // [256][256][256]
{
    __shared__ alignas(16) float L[4][64][68];  // 69632 B; slice [w] wave-private pre-barrier

    const int tid  = threadIdx.x;
    const int b    = blockIdx.x;
    const int w    = tid >> 6;
    const int lane = tid & 63;
    const int pyp  = lane >> 3, qyp = lane & 7;   // producer post-transpose identity

    // epilogue work identity (all threads): 512 = 16 qg x 2 cs-half x 16 sp-local
    const int qg  = tid & 15;
    const int csh = (tid >> 4) & 1;
    const int spl = tid >> 5;                     // 0..15

    float e0[4], e1[4];
#pragma unroll
    for (int c = 0; c < 4; ++c) { e0[c] = uc[c*4+2]; e1[c] = uc[c*4+3]; }
    float* ob = out + (size_t)b * 65536;

    float Y[64];  // producers: Y[px][qx'] after qx-contraction; live through strip loop

    if (w < 4) {  // producer waves (whole waves, no intra-wave divergence)
        const int c1 = w >> 1, c2 = w & 1;
        const int px = lane >> 3, qx = lane & 7;
        const float* rb = rho + (size_t)b * 16384
                        + (size_t)((c1 << 6) + (px << 3)) * 128 + (c2 << 6) + (qx << 3);

        float X[64];
        // load X[py][qy]: 16 x b128
#pragma unroll
        for (int py = 0; py < 8; ++py) {
            float4 lo = *(const float4*)(rb + py * 128);
            float4 hi = *(const float4*)(rb + py * 128 + 4);
            X[py*8+0]=lo.x; X[py*8+1]=lo.y; X[py*8+2]=lo.z; X[py*8+3]=lo.w;
            X[py*8+4]=hi.x; X[py*8+5]=hi.y; X[py*8+6]=hi.z; X[py*8+7]=hi.w;
        }
        // contract qy (row-local: FMAs start as rows arrive)
#pragma unroll
        for (int py = 0; py < 8; ++py)
#pragma unroll
            for (int j = 0; j < 8; ++j) {
                float acc = 0.f;
#pragma unroll
                for (int k = 0; k < 8; ++k) acc += uy[j*8+k] * X[py*8+k];
                Y[py*8+j] = acc;
            }
        // contract py
#pragma unroll
        for (int i = 0; i < 8; ++i)
#pragma unroll
            for (int j = 0; j < 8; ++j) {
                float acc = 0.f;
#pragma unroll
                for (int k = 0; k < 8; ++k) acc += uy[i*8+k] * Y[k*8+j];
                X[i*8+j] = acc;
            }
        // wave-private transpose: (in-thread py',qy') <-> (lane px,qx)
#pragma unroll
        for (int e = 0; e < 64; ++e) L[w][e][lane] = X[e];       // conflict-free
        __asm__ volatile("s_waitcnt lgkmcnt(0)" ::: "memory");   // DS in-order per wave
#pragma unroll
        for (int f4 = 0; f4 < 16; ++f4) {
            float4 v = *(const float4*)&L[w][lane][f4 * 4];
            X[f4*4+0]=v.x; X[f4*4+1]=v.y; X[f4*4+2]=v.z; X[f4*4+3]=v.w;
        }
        // contract qx: Y[px][qx'] = sum_k ux[qx'][k] X[px][k]
#pragma unroll
        for (int p = 0; p < 8; ++p)
#pragma unroll
            for (int j = 0; j < 8; ++j) {
                float acc = 0.f;
#pragma unroll
                for (int k = 0; k < 8; ++k) acc += ux[j*8+k] * X[p*8+k];
                Y[p*8+j] = acc;
            }
    }

    // strip loop: producers finish W rows 2s,2s+1; everyone stores strip s (sp in [16s,16s+16))
    // Barriers are LDS-only: global stores from strip s-1 stay in flight.
#pragma unroll
    for (int s = 0; s < 4; ++s) {
        if (w < 4) {
#pragma unroll
            for (int i2 = 0; i2 < 2; ++i2) {
                const int i = 2*s + i2;   // px'
#pragma unroll
                for (int j = 0; j < 8; ++j) {
                    float acc = 0.f;
#pragma unroll
                    for (int k = 0; k < 8; ++k) acc += ux[i*8+k] * Y[k*8+j];
                    L[w][i*8+pyp][j*8+qyp] = acc;   // <=2-way banks: free
                }
            }
        }
        BARRIER_LDS_ONLY();  // strip s W visible (disjoint LDS rows vs other strips)

        const int sp = 16*s + spl;
        float4 wv[4];
#pragma unroll
        for (int ww = 0; ww < 4; ++ww) wv[ww] = *(const float4*)&L[ww][sp][qg * 4];
#pragma unroll
        for (int c = 0; c < 4; ++c) {
#pragma unroll
            for (int cs2 = 0; cs2 < 2; ++cs2) {
                const int cs = 2*csh + cs2;
                const float k00 = e0[c]*e0[cs], k01 = e0[c]*e1[cs];
                const float k10 = e1[c]*e0[cs], k11 = e1[c]*e1[cs];
                float4 v;
                v.x = k00*wv[0].x + k01*wv[1].x + k10*wv[2].x + k11*wv[3].x;
                v.y = k00*wv[0].y + k01*wv[1].y + k10*wv[2].y + k11*wv[3].y;
                v.z = k00*wv[0].z + k01*wv[1].z + k10*wv[2].z + k11*wv[3].z;
                v.w = k00*wv[0].w + k01*wv[1].w + k10*wv[2].w + k11*wv[3].w;
                *(float4*)&ob[(size_t)((c*64 + sp) * 256 + cs*64 + qg*4)] = v;
            }
        }
    }
}

extern "C" void kernel_launch(void* const* d_in, const int* in_sizes, int n_in,
                              void* d_out, int out_size, void* d_ws, size_t ws_size,
                              hipStream_t stream) {
    const float* rho = (const float*)d_in[0];
    const float* ux  = (const float*)d_in[1];
    const float* uy  = (const float*)d_in[2];
    const float* uc  = (const float*)d_in[3];
    float* out = (float*)d_out;
    qconv_fused<<<dim3(256), dim3(TPB), 0, stream>>>(rho, ux, uy, uc, out);
}